// Round 3
// baseline (181.647 us; speedup 1.0000x reference)
//
#include <hip/hip_runtime.h>
#include <hip/hip_bf16.h>

typedef __attribute__((ext_vector_type(8))) short short8;
typedef __attribute__((ext_vector_type(4))) float f32x4;
typedef __attribute__((ext_vector_type(4))) unsigned int u32x4;
typedef __attribute__((ext_vector_type(2))) unsigned int u32x2;

#define DFEAT 128
#define LDW 136   // Wt row stride in shorts (+8 pad -> 8-deep uniform banks, conflict-free for b128)

__device__ __forceinline__ unsigned short f2bf(float f) {
    unsigned int u = __float_as_uint(f);
    u += 0x7FFFu + ((u >> 16) & 1u);   // round-nearest-even
    return (unsigned short)(u >> 16);
}
__device__ __forceinline__ unsigned int packbf2(float lo, float hi) {
    return (unsigned int)f2bf(lo) | ((unsigned int)f2bf(hi) << 16);
}
__device__ __forceinline__ float bf2f(unsigned int bits) {
    return __uint_as_float(bits << 16);
}

// Phase 1: A[n][:] = zi[n] @ W1[0:128][:] + b1   (table 0 = blockIdx.y 0)
//          B[n][:] = zj[n] @ W1[128:256][:]      (table 1)
// One wave computes a 16-row x 128-col strip. MFMA operands SWAPPED
// (A = W^T fragment, B = z fragment) so D's M-index is the output column:
// lane (l15,kg) holds z-row strip*16+l15, cols ct*16+kg*4+{0..3} -> packed 8B stores.
__global__ __launch_bounds__(256, 4) void node_gemm(
    const float* __restrict__ zi, const float* __restrict__ zj,
    const float* __restrict__ W1, const float* __restrict__ b1,
    unsigned short* __restrict__ Aout, unsigned short* __restrict__ Bout,
    int nN)
{
    __shared__ unsigned short Wt[128][LDW];   // Wt[col][k] bf16
    __shared__ float bias_lds[128];
    const int table = blockIdx.y;
    const float* __restrict__ z = table ? zj : zi;
    unsigned short* __restrict__ outp = table ? Bout : Aout;

    // stage W-half transposed as bf16 (vectorized float4 global reads)
    for (int i = threadIdx.x; i < 128 * 32; i += 256) {
        int k = i >> 5, c4 = (i & 31) * 4;
        float4 w = *(const float4*)&W1[(size_t)(table * 128 + k) * DFEAT + c4];
        Wt[c4 + 0][k] = f2bf(w.x);
        Wt[c4 + 1][k] = f2bf(w.y);
        Wt[c4 + 2][k] = f2bf(w.z);
        Wt[c4 + 3][k] = f2bf(w.w);
    }
    if (threadIdx.x < 128) bias_lds[threadIdx.x] = table ? 0.f : b1[threadIdx.x];
    __syncthreads();

    const int lane = threadIdx.x & 63;
    const int l15  = lane & 15;
    const int kg   = lane >> 4;          // 0..3
    int wv = blockIdx.x * 4 + (threadIdx.x >> 6);
    int nw = gridDim.x * 4;
    int nStrips = (nN + 15) >> 4;

    float4 cur[8];
    int s = wv;
    if (s < nStrips) {
        int row = s * 16 + l15;
        const float* zr = z + (size_t)(row < nN ? row : nN - 1) * DFEAT + kg * 8;
#pragma unroll
        for (int kk = 0; kk < 4; ++kk) {
            cur[2 * kk]     = *(const float4*)(zr + kk * 32);
            cur[2 * kk + 1] = *(const float4*)(zr + kk * 32 + 4);
        }
    }

    while (s < nStrips) {
        // 1) convert current strip floats -> bf16 B-fragments (frees cur)
        short8 bf[4];
#pragma unroll
        for (int kk = 0; kk < 4; ++kk) {
            union { unsigned int u[4]; short8 s8; } cv;
            cv.u[0] = packbf2(cur[2 * kk].x,     cur[2 * kk].y);
            cv.u[1] = packbf2(cur[2 * kk].z,     cur[2 * kk].w);
            cv.u[2] = packbf2(cur[2 * kk + 1].x, cur[2 * kk + 1].y);
            cv.u[3] = packbf2(cur[2 * kk + 1].z, cur[2 * kk + 1].w);
            bf[kk] = cv.s8;
        }

        // 2) prefetch next strip into the same registers (overlaps MFMA+store)
        int snext = s + nw;
        if (snext < nStrips) {
            int row = snext * 16 + l15;
            const float* zr = z + (size_t)(row < nN ? row : nN - 1) * DFEAT + kg * 8;
#pragma unroll
            for (int kk = 0; kk < 4; ++kk) {
                cur[2 * kk]     = *(const float4*)(zr + kk * 32);
                cur[2 * kk + 1] = *(const float4*)(zr + kk * 32 + 4);
            }
        }

        // 3) acc init = bias (broadcast LDS read), then 32 MFMA
        f32x4 acc[8];
#pragma unroll
        for (int ct = 0; ct < 8; ++ct)
            acc[ct] = *(const f32x4*)&bias_lds[ct * 16 + kg * 4];
#pragma unroll
        for (int kk = 0; kk < 4; ++kk) {
#pragma unroll
            for (int ct = 0; ct < 8; ++ct) {
                short8 a = *(const short8*)&Wt[ct * 16 + l15][kk * 32 + kg * 8];
                acc[ct] = __builtin_amdgcn_mfma_f32_16x16x32_bf16(a, bf[kk], acc[ct], 0, 0, 0);
            }
        }

        // 4) packed epilogue: lane writes 4 consecutive bf16 cols per ct (8B each)
        int row = s * 16 + l15;
        if (row < nN) {
            unsigned short* op = outp + (size_t)row * DFEAT + kg * 4;
#pragma unroll
            for (int ct = 0; ct < 8; ++ct) {
                u32x2 v;
                v[0] = packbf2(acc[ct][0], acc[ct][1]);
                v[1] = packbf2(acc[ct][2], acc[ct][3]);
                *(u32x2*)(op + ct * 16) = v;
            }
        }
        s = snext;
    }
}

// Phase 2: 16 lanes per edge, 8 edges/wave/iter (2 quads unrolled).
__global__ __launch_bounds__(256) void edge_kernel(
    const unsigned short* __restrict__ A, const unsigned short* __restrict__ B,
    const int* __restrict__ src, const int* __restrict__ dst,
    const float* __restrict__ W3, const float* __restrict__ b3,
    float* __restrict__ out, int nE)
{
    const int lane = threadIdx.x & 63;
    const int sub  = lane & 15;     // position within edge group
    const int grp  = lane >> 4;     // which edge of the quad

    float w3v[8];
#pragma unroll
    for (int j = 0; j < 8; ++j) w3v[j] = W3[sub * 8 + j];
    const float bb = b3[0];

    int wv = blockIdx.x * 4 + (threadIdx.x >> 6);
    int nw = gridDim.x * 4;

    for (int base = wv * 8; base < nE; base += nw * 8) {
        int e0 = base + grp;
        int e1 = base + 4 + grp;
        bool v0 = e0 < nE, v1 = e1 < nE;
        int s0 = v0 ? src[e0] : 0, d0 = v0 ? dst[e0] : 0;
        int s1 = v1 ? src[e1] : 0, d1 = v1 ? dst[e1] : 0;

        const u32x4* pa0 = (const u32x4*)(A + (size_t)s0 * DFEAT + sub * 8);
        const u32x4* pb0 = (const u32x4*)(B + (size_t)d0 * DFEAT + sub * 8);
        const u32x4* pa1 = (const u32x4*)(A + (size_t)s1 * DFEAT + sub * 8);
        const u32x4* pb1 = (const u32x4*)(B + (size_t)d1 * DFEAT + sub * 8);
        u32x4 av0 = *pa0, bv0 = *pb0;
        u32x4 av1 = *pa1, bv1 = *pb1;

        float p0 = 0.f, p1 = 0.f;
#pragma unroll
        for (int w = 0; w < 4; ++w) {
            float x0 = fmaxf(bf2f(av0[w] & 0xFFFFu) + bf2f(bv0[w] & 0xFFFFu), 0.f);
            float x1 = fmaxf(bf2f(av0[w] >> 16)     + bf2f(bv0[w] >> 16),     0.f);
            p0 = fmaf(x0, w3v[w * 2], p0);
            p0 = fmaf(x1, w3v[w * 2 + 1], p0);
            float y0 = fmaxf(bf2f(av1[w] & 0xFFFFu) + bf2f(bv1[w] & 0xFFFFu), 0.f);
            float y1 = fmaxf(bf2f(av1[w] >> 16)     + bf2f(bv1[w] >> 16),     0.f);
            p1 = fmaf(y0, w3v[w * 2], p1);
            p1 = fmaf(y1, w3v[w * 2 + 1], p1);
        }
#pragma unroll
        for (int off = 8; off > 0; off >>= 1) {
            p0 += __shfl_xor(p0, off, 64);
            p1 += __shfl_xor(p1, off, 64);
        }
        if (sub == 0) {
            if (v0) out[e0] = 1.f / (1.f + __expf(-(p0 + bb)));
            if (v1) out[e1] = 1.f / (1.f + __expf(-(p1 + bb)));
        }
    }
}

// Fallback (only if d_ws too small): direct per-edge dense compute. Slow, correct.
__global__ __launch_bounds__(256) void fallback_kernel(
    const float* __restrict__ zi, const float* __restrict__ zj,
    const int* __restrict__ src, const int* __restrict__ dst,
    const float* __restrict__ W1, const float* __restrict__ b1,
    const float* __restrict__ W3, const float* __restrict__ b3,
    float* __restrict__ out, int nE)
{
    int e = blockIdx.x * blockDim.x + threadIdx.x;
    if (e >= nE) return;
    const float* a = zi + (size_t)src[e] * DFEAT;
    const float* b = zj + (size_t)dst[e] * DFEAT;
    float logit = b3[0];
    for (int h = 0; h < 128; ++h) {
        float acc = b1[h];
        for (int k = 0; k < 128; ++k) acc = fmaf(a[k], W1[(size_t)k * 128 + h], acc);
        for (int k = 0; k < 128; ++k) acc = fmaf(b[k], W1[(size_t)(128 + k) * 128 + h], acc);
        if (acc > 0.f) logit = fmaf(acc, W3[h], logit);
    }
    out[e] = 1.f / (1.f + __expf(-logit));
}

extern "C" void kernel_launch(void* const* d_in, const int* in_sizes, int n_in,
                              void* d_out, int out_size, void* d_ws, size_t ws_size,
                              hipStream_t stream) {
    const float* zi = (const float*)d_in[0];
    const float* zj = (const float*)d_in[1];
    const int*  src = (const int*)d_in[2];
    const int*  dst = (const int*)d_in[3];
    const float* W1 = (const float*)d_in[4];
    const float* b1 = (const float*)d_in[5];
    const float* W3 = (const float*)d_in[6];
    const float* b3 = (const float*)d_in[7];
    float* out = (float*)d_out;

    int nN = in_sizes[0] / DFEAT;
    int nE = in_sizes[2];
    size_t abytes = (size_t)nN * DFEAT * sizeof(unsigned short);

    if (ws_size >= 2 * abytes) {
        unsigned short* A = (unsigned short*)d_ws;
        unsigned short* B = A + (size_t)nN * DFEAT;
        // X=521: 2084 waves/table, 6250 strips -> exactly 3 strips/wave (6252)
        dim3 g1(521, 2, 1);
        node_gemm<<<g1, 256, 0, stream>>>(zi, zj, W1, b1, A, B, nN);
        edge_kernel<<<2048, 256, 0, stream>>>(A, B, src, dst, W3, b3, out, nE);
    } else {
        fallback_kernel<<<(nE + 255) / 256, 256, 0, stream>>>(
            zi, zj, src, dst, W1, b1, W3, b3, out, nE);
    }
}

// Round 4
// 87.096 us; speedup vs baseline: 2.0856x; 2.0856x over previous
//
#include <hip/hip_runtime.h>
#include <hip/hip_bf16.h>

typedef __attribute__((ext_vector_type(8))) short short8;
typedef __attribute__((ext_vector_type(4))) float f32x4;
typedef __attribute__((ext_vector_type(4))) unsigned int u32x4;
typedef __attribute__((ext_vector_type(2))) unsigned int u32x2;

#define DFEAT 128
#define LDW 136   // Wt row stride in shorts; 272B rows stay 16B-aligned for b128 reads

__device__ __forceinline__ unsigned short f2bf(float f) {
    unsigned int u = __float_as_uint(f);
    u += 0x7FFFu + ((u >> 16) & 1u);   // round-nearest-even
    return (unsigned short)(u >> 16);
}
__device__ __forceinline__ unsigned int packbf2(float lo, float hi) {
    return (unsigned int)f2bf(lo) | ((unsigned int)f2bf(hi) << 16);
}
__device__ __forceinline__ float bf2f(unsigned int bits) {
    return __uint_as_float(bits << 16);
}

// Phase 1: A[n][:] = zi[n] @ W1[0:128][:] + b1   (table 0)
//          B[n][:] = zj[n] @ W1[128:256][:]      (table 1)
// One wave per 16-row x 128-col strip. MFMA operands swapped (A=W^T frag,
// B=z frag) so lane (l15,kg) holds z-row strip*16+l15, cols ct*16+kg*4+{0..3}
// -> packed 8B stores. Register double-buffer on z; acc split in two 4-tile
// halves to keep VGPR <= 128 (16 waves/CU; LDS 35.3KB -> 4 blocks/CU).
__global__ __launch_bounds__(256) void node_gemm(
    const float* __restrict__ zi, const float* __restrict__ zj,
    const float* __restrict__ W1, const float* __restrict__ b1,
    unsigned short* __restrict__ Aout, unsigned short* __restrict__ Bout,
    int nN)
{
    __shared__ unsigned short Wt[128][LDW];   // Wt[col][k] bf16
    __shared__ float bias_lds[128];
    const int table = blockIdx.y;
    const float* __restrict__ z = table ? zj : zi;
    unsigned short* __restrict__ outp = table ? Bout : Aout;

    // stage W-half transposed as bf16 (coalesced scalar reads; LDS writes 4-way max)
    for (int idx = threadIdx.x; idx < 128 * 128; idx += 256) {
        int c = idx & 127, k = idx >> 7;
        Wt[c][k] = f2bf(W1[(size_t)(table * 128 + k) * DFEAT + c]);
    }
    if (threadIdx.x < 128) bias_lds[threadIdx.x] = table ? 0.f : b1[threadIdx.x];
    __syncthreads();

    const int lane = threadIdx.x & 63;
    const int l15  = lane & 15;
    const int kg   = lane >> 4;          // 0..3
    int wv = blockIdx.x * 4 + (threadIdx.x >> 6);
    int nw = gridDim.x * 4;
    int nStrips = (nN + 15) >> 4;

    float4 cur[8];
    int s = wv;
    if (s < nStrips) {
        int row = s * 16 + l15;
        const float* zr = z + (size_t)(row < nN ? row : nN - 1) * DFEAT + kg * 8;
#pragma unroll
        for (int kk = 0; kk < 4; ++kk) {
            cur[2 * kk]     = *(const float4*)(zr + kk * 32);
            cur[2 * kk + 1] = *(const float4*)(zr + kk * 32 + 4);
        }
    }

    while (s < nStrips) {
        // 1) convert current strip fp32 -> bf16 B-fragments (frees cur)
        short8 bf[4];
#pragma unroll
        for (int kk = 0; kk < 4; ++kk) {
            union { unsigned int u[4]; short8 s8; } cv;
            cv.u[0] = packbf2(cur[2 * kk].x,     cur[2 * kk].y);
            cv.u[1] = packbf2(cur[2 * kk].z,     cur[2 * kk].w);
            cv.u[2] = packbf2(cur[2 * kk + 1].x, cur[2 * kk + 1].y);
            cv.u[3] = packbf2(cur[2 * kk + 1].z, cur[2 * kk + 1].w);
            bf[kk] = cv.s8;
        }

        // 2) prefetch next strip into cur (overlaps both MFMA halves + stores)
        int snext = s + nw;
        if (snext < nStrips) {
            int row = snext * 16 + l15;
            const float* zr = z + (size_t)(row < nN ? row : nN - 1) * DFEAT + kg * 8;
#pragma unroll
            for (int kk = 0; kk < 4; ++kk) {
                cur[2 * kk]     = *(const float4*)(zr + kk * 32);
                cur[2 * kk + 1] = *(const float4*)(zr + kk * 32 + 4);
            }
        }

        // 3) two halves of 4 ct-tiles each: acc stays at 16 VGPRs
        int row = s * 16 + l15;
        unsigned short* op = outp + (size_t)row * DFEAT + kg * 4;
#pragma unroll
        for (int h = 0; h < 2; ++h) {
            f32x4 acc[4];
#pragma unroll
            for (int ci = 0; ci < 4; ++ci)
                acc[ci] = *(const f32x4*)&bias_lds[(h * 4 + ci) * 16 + kg * 4];
#pragma unroll
            for (int kk = 0; kk < 4; ++kk) {
#pragma unroll
                for (int ci = 0; ci < 4; ++ci) {
                    short8 a = *(const short8*)&Wt[(h * 4 + ci) * 16 + l15][kk * 32 + kg * 8];
                    acc[ci] = __builtin_amdgcn_mfma_f32_16x16x32_bf16(a, bf[kk], acc[ci], 0, 0, 0);
                }
            }
            if (row < nN) {
#pragma unroll
                for (int ci = 0; ci < 4; ++ci) {
                    u32x2 v;
                    v[0] = packbf2(acc[ci][0], acc[ci][1]);
                    v[1] = packbf2(acc[ci][2], acc[ci][3]);
                    *(u32x2*)(op + (h * 4 + ci) * 16) = v;
                }
            }
        }
        s = snext;
    }
}

// Phase 2: 16 lanes per edge, 8 edges/wave/iter (2 quads unrolled).
__global__ __launch_bounds__(256) void edge_kernel(
    const unsigned short* __restrict__ A, const unsigned short* __restrict__ B,
    const int* __restrict__ src, const int* __restrict__ dst,
    const float* __restrict__ W3, const float* __restrict__ b3,
    float* __restrict__ out, int nE)
{
    const int lane = threadIdx.x & 63;
    const int sub  = lane & 15;     // position within edge group
    const int grp  = lane >> 4;     // which edge of the quad

    float w3v[8];
#pragma unroll
    for (int j = 0; j < 8; ++j) w3v[j] = W3[sub * 8 + j];
    const float bb = b3[0];

    int wv = blockIdx.x * 4 + (threadIdx.x >> 6);
    int nw = gridDim.x * 4;

    for (int base = wv * 8; base < nE; base += nw * 8) {
        int e0 = base + grp;
        int e1 = base + 4 + grp;
        bool v0 = e0 < nE, v1 = e1 < nE;
        int s0 = v0 ? src[e0] : 0, d0 = v0 ? dst[e0] : 0;
        int s1 = v1 ? src[e1] : 0, d1 = v1 ? dst[e1] : 0;

        const u32x4* pa0 = (const u32x4*)(A + (size_t)s0 * DFEAT + sub * 8);
        const u32x4* pb0 = (const u32x4*)(B + (size_t)d0 * DFEAT + sub * 8);
        const u32x4* pa1 = (const u32x4*)(A + (size_t)s1 * DFEAT + sub * 8);
        const u32x4* pb1 = (const u32x4*)(B + (size_t)d1 * DFEAT + sub * 8);
        u32x4 av0 = *pa0, bv0 = *pb0;
        u32x4 av1 = *pa1, bv1 = *pb1;

        float p0 = 0.f, p1 = 0.f;
#pragma unroll
        for (int w = 0; w < 4; ++w) {
            float x0 = fmaxf(bf2f(av0[w] & 0xFFFFu) + bf2f(bv0[w] & 0xFFFFu), 0.f);
            float x1 = fmaxf(bf2f(av0[w] >> 16)     + bf2f(bv0[w] >> 16),     0.f);
            p0 = fmaf(x0, w3v[w * 2], p0);
            p0 = fmaf(x1, w3v[w * 2 + 1], p0);
            float y0 = fmaxf(bf2f(av1[w] & 0xFFFFu) + bf2f(bv1[w] & 0xFFFFu), 0.f);
            float y1 = fmaxf(bf2f(av1[w] >> 16)     + bf2f(bv1[w] >> 16),     0.f);
            p1 = fmaf(y0, w3v[w * 2], p1);
            p1 = fmaf(y1, w3v[w * 2 + 1], p1);
        }
#pragma unroll
        for (int off = 8; off > 0; off >>= 1) {
            p0 += __shfl_xor(p0, off, 64);
            p1 += __shfl_xor(p1, off, 64);
        }
        if (sub == 0) {
            if (v0) out[e0] = 1.f / (1.f + __expf(-(p0 + bb)));
            if (v1) out[e1] = 1.f / (1.f + __expf(-(p1 + bb)));
        }
    }
}

// Fallback (only if d_ws too small): direct per-edge dense compute. Slow, correct.
__global__ __launch_bounds__(256) void fallback_kernel(
    const float* __restrict__ zi, const float* __restrict__ zj,
    const int* __restrict__ src, const int* __restrict__ dst,
    const float* __restrict__ W1, const float* __restrict__ b1,
    const float* __restrict__ W3, const float* __restrict__ b3,
    float* __restrict__ out, int nE)
{
    int e = blockIdx.x * blockDim.x + threadIdx.x;
    if (e >= nE) return;
    const float* a = zi + (size_t)src[e] * DFEAT;
    const float* b = zj + (size_t)dst[e] * DFEAT;
    float logit = b3[0];
    for (int h = 0; h < 128; ++h) {
        float acc = b1[h];
        for (int k = 0; k < 128; ++k) acc = fmaf(a[k], W1[(size_t)k * 128 + h], acc);
        for (int k = 0; k < 128; ++k) acc = fmaf(b[k], W1[(size_t)(128 + k) * 128 + h], acc);
        if (acc > 0.f) logit = fmaf(acc, W3[h], logit);
    }
    out[e] = 1.f / (1.f + __expf(-logit));
}

extern "C" void kernel_launch(void* const* d_in, const int* in_sizes, int n_in,
                              void* d_out, int out_size, void* d_ws, size_t ws_size,
                              hipStream_t stream) {
    const float* zi = (const float*)d_in[0];
    const float* zj = (const float*)d_in[1];
    const int*  src = (const int*)d_in[2];
    const int*  dst = (const int*)d_in[3];
    const float* W1 = (const float*)d_in[4];
    const float* b1 = (const float*)d_in[5];
    const float* W3 = (const float*)d_in[6];
    const float* b3 = (const float*)d_in[7];
    float* out = (float*)d_out;

    int nN = in_sizes[0] / DFEAT;
    int nE = in_sizes[2];
    size_t abytes = (size_t)nN * DFEAT * sizeof(unsigned short);

    if (ws_size >= 2 * abytes) {
        unsigned short* A = (unsigned short*)d_ws;
        unsigned short* B = A + (size_t)nN * DFEAT;
        // X=521: 2084 waves/table, 6250 strips -> exactly 3 strips/wave
        dim3 g1(521, 2, 1);
        node_gemm<<<g1, 256, 0, stream>>>(zi, zj, W1, b1, A, B, nN);
        edge_kernel<<<2048, 256, 0, stream>>>(A, B, src, dst, W3, b3, out, nE);
    } else {
        fallback_kernel<<<(nE + 255) / 256, 256, 0, stream>>>(
            zi, zj, src, dst, W1, b1, W3, b3, out, nE);
    }
}

// Round 6
// 80.565 us; speedup vs baseline: 2.2547x; 1.0811x over previous
//
#include <hip/hip_runtime.h>
#include <hip/hip_bf16.h>

typedef __attribute__((ext_vector_type(8))) short short8;
typedef __attribute__((ext_vector_type(4))) float f32x4;
typedef __attribute__((ext_vector_type(4))) unsigned int u32x4;
typedef __attribute__((ext_vector_type(2))) unsigned int u32x2;

#define DFEAT 128
#define LDW 136   // Wt row stride in shorts: 272B rows -> 4-bank row shift, b128-friendly

__device__ __forceinline__ unsigned short f2bf(float f) {
    unsigned int u = __float_as_uint(f);
    u += 0x7FFFu + ((u >> 16) & 1u);   // round-nearest-even
    return (unsigned short)(u >> 16);
}
// packed f32x2 -> bf16x2, RNE, single instruction (gfx950 v_cvt_pk_bf16_f32)
__device__ __forceinline__ unsigned int cvt2(float lo, float hi) {
    unsigned int r;
    asm("v_cvt_pk_bf16_f32 %0, %1, %2" : "=v"(r) : "v"(lo), "v"(hi));
    return r;
}
__device__ __forceinline__ float bf2f(unsigned int bits) {
    return __uint_as_float(bits << 16);
}

// Phase 1: A[n][:] = zi[n] @ W1[0:128][:] + b1   (table 0)
//          B[n][:] = zj[n] @ W1[128:256][:]      (table 1)
// One wave per 16-row x 128-col strip. MFMA operands swapped (A=W^T frag,
// B=z frag) so lane (l15,kg) holds z-row strip*16+l15, cols ct*16+kg*4+{0..3}
// -> packed 8B stores. Register double-buffer on z; acc split in two 4-tile
// halves keeps VGPR <= 128 (proven round 4). Grid x=512 -> exactly 1024
// blocks = 4/CU residency, no straggler round (round-4 used 521 -> 18-block tail).
__global__ __launch_bounds__(256) void node_gemm(
    const float* __restrict__ zi, const float* __restrict__ zj,
    const float* __restrict__ W1, const float* __restrict__ b1,
    unsigned short* __restrict__ Aout, unsigned short* __restrict__ Bout,
    int nN)
{
    __shared__ unsigned short Wt[128][LDW];   // Wt[col][k] bf16
    __shared__ float bias_lds[128];
    const int table = blockIdx.y;
    const float* __restrict__ z = table ? zj : zi;
    unsigned short* __restrict__ outp = table ? Bout : Aout;

    // stage W-half transposed as bf16 (coalesced scalar reads; benign LDS write conflicts)
    for (int idx = threadIdx.x; idx < 128 * 128; idx += 256) {
        int c = idx & 127, k = idx >> 7;
        Wt[c][k] = f2bf(W1[(size_t)(table * 128 + k) * DFEAT + c]);
    }
    if (threadIdx.x < 128) bias_lds[threadIdx.x] = table ? 0.f : b1[threadIdx.x];
    __syncthreads();

    const int lane = threadIdx.x & 63;
    const int l15  = lane & 15;
    const int kg   = lane >> 4;          // 0..3
    int wv = blockIdx.x * 4 + (threadIdx.x >> 6);
    int nw = gridDim.x * 4;
    int nStrips = (nN + 15) >> 4;

    float4 cur[8];
    int s = wv;
    if (s < nStrips) {
        int row = s * 16 + l15;
        const float* zr = z + (size_t)(row < nN ? row : nN - 1) * DFEAT + kg * 8;
#pragma unroll
        for (int kk = 0; kk < 4; ++kk) {
            cur[2 * kk]     = *(const float4*)(zr + kk * 32);
            cur[2 * kk + 1] = *(const float4*)(zr + kk * 32 + 4);
        }
    }

    while (s < nStrips) {
        // 1) convert current strip fp32 -> bf16 B-fragments (16x cvt_pk; frees cur)
        short8 bf[4];
#pragma unroll
        for (int kk = 0; kk < 4; ++kk) {
            union { unsigned int u[4]; short8 s8; } cv;
            cv.u[0] = cvt2(cur[2 * kk].x,     cur[2 * kk].y);
            cv.u[1] = cvt2(cur[2 * kk].z,     cur[2 * kk].w);
            cv.u[2] = cvt2(cur[2 * kk + 1].x, cur[2 * kk + 1].y);
            cv.u[3] = cvt2(cur[2 * kk + 1].z, cur[2 * kk + 1].w);
            bf[kk] = cv.s8;
        }

        // 2) prefetch next strip into cur (overlaps both MFMA halves + stores)
        int snext = s + nw;
        if (snext < nStrips) {
            int row = snext * 16 + l15;
            const float* zr = z + (size_t)(row < nN ? row : nN - 1) * DFEAT + kg * 8;
#pragma unroll
            for (int kk = 0; kk < 4; ++kk) {
                cur[2 * kk]     = *(const float4*)(zr + kk * 32);
                cur[2 * kk + 1] = *(const float4*)(zr + kk * 32 + 4);
            }
        }

        // 3) two halves of 4 ct-tiles each: acc stays at 16 VGPRs
        int row = s * 16 + l15;
        unsigned short* op = outp + (size_t)row * DFEAT + kg * 4;
#pragma unroll
        for (int h = 0; h < 2; ++h) {
            f32x4 acc[4];
#pragma unroll
            for (int ci = 0; ci < 4; ++ci)
                acc[ci] = *(const f32x4*)&bias_lds[(h * 4 + ci) * 16 + kg * 4];
#pragma unroll
            for (int kk = 0; kk < 4; ++kk) {
#pragma unroll
                for (int ci = 0; ci < 4; ++ci) {
                    short8 a = *(const short8*)&Wt[(h * 4 + ci) * 16 + l15][kk * 32 + kg * 8];
                    acc[ci] = __builtin_amdgcn_mfma_f32_16x16x32_bf16(a, bf[kk], acc[ci], 0, 0, 0);
                }
            }
            if (row < nN) {
#pragma unroll
                for (int ci = 0; ci < 4; ++ci) {
                    u32x2 v;
                    v[0] = cvt2(acc[ci][0], acc[ci][1]);
                    v[1] = cvt2(acc[ci][2], acc[ci][3]);
                    *(u32x2*)(op + (h * 4 + ci) * 16) = v;
                }
            }
        }
        s = snext;
    }
}

// Phase 2: 16 lanes per edge, 8 edges/wave/iter (2 quads unrolled).
__global__ __launch_bounds__(256) void edge_kernel(
    const unsigned short* __restrict__ A, const unsigned short* __restrict__ B,
    const int* __restrict__ src, const int* __restrict__ dst,
    const float* __restrict__ W3, const float* __restrict__ b3,
    float* __restrict__ out, int nE)
{
    const int lane = threadIdx.x & 63;
    const int sub  = lane & 15;
    const int grp  = lane >> 4;

    float w3v[8];
#pragma unroll
    for (int j = 0; j < 8; ++j) w3v[j] = W3[sub * 8 + j];
    const float bb = b3[0];

    int wv = blockIdx.x * 4 + (threadIdx.x >> 6);
    int nw = gridDim.x * 4;

    for (int base = wv * 8; base < nE; base += nw * 8) {
        int e0 = base + grp;
        int e1 = base + 4 + grp;
        bool v0 = e0 < nE, v1 = e1 < nE;
        int s0 = v0 ? src[e0] : 0, d0 = v0 ? dst[e0] : 0;
        int s1 = v1 ? src[e1] : 0, d1 = v1 ? dst[e1] : 0;

        const u32x4* pa0 = (const u32x4*)(A + (size_t)s0 * DFEAT + sub * 8);
        const u32x4* pb0 = (const u32x4*)(B + (size_t)d0 * DFEAT + sub * 8);
        const u32x4* pa1 = (const u32x4*)(A + (size_t)s1 * DFEAT + sub * 8);
        const u32x4* pb1 = (const u32x4*)(B + (size_t)d1 * DFEAT + sub * 8);
        u32x4 av0 = *pa0, bv0 = *pb0;
        u32x4 av1 = *pa1, bv1 = *pb1;

        float p0 = 0.f, p1 = 0.f;
#pragma unroll
        for (int w = 0; w < 4; ++w) {
            float x0 = fmaxf(bf2f(av0[w] & 0xFFFFu) + bf2f(bv0[w] & 0xFFFFu), 0.f);
            float x1 = fmaxf(bf2f(av0[w] >> 16)     + bf2f(bv0[w] >> 16),     0.f);
            p0 = fmaf(x0, w3v[w * 2], p0);
            p0 = fmaf(x1, w3v[w * 2 + 1], p0);
            float y0 = fmaxf(bf2f(av1[w] & 0xFFFFu) + bf2f(bv1[w] & 0xFFFFu), 0.f);
            float y1 = fmaxf(bf2f(av1[w] >> 16)     + bf2f(bv1[w] >> 16),     0.f);
            p1 = fmaf(y0, w3v[w * 2], p1);
            p1 = fmaf(y1, w3v[w * 2 + 1], p1);
        }
#pragma unroll
        for (int off = 8; off > 0; off >>= 1) {
            p0 += __shfl_xor(p0, off, 64);
            p1 += __shfl_xor(p1, off, 64);
        }
        if (sub == 0) {
            if (v0) out[e0] = 1.f / (1.f + __expf(-(p0 + bb)));
            if (v1) out[e1] = 1.f / (1.f + __expf(-(p1 + bb)));
        }
    }
}

// Fallback (only if d_ws too small): direct per-edge dense compute. Slow, correct.
__global__ __launch_bounds__(256) void fallback_kernel(
    const float* __restrict__ zi, const float* __restrict__ zj,
    const int* __restrict__ src, const int* __restrict__ dst,
    const float* __restrict__ W1, const float* __restrict__ b1,
    const float* __restrict__ W3, const float* __restrict__ b3,
    float* __restrict__ out, int nE)
{
    int e = blockIdx.x * blockDim.x + threadIdx.x;
    if (e >= nE) return;
    const float* a = zi + (size_t)src[e] * DFEAT;
    const float* b = zj + (size_t)dst[e] * DFEAT;
    float logit = b3[0];
    for (int h = 0; h < 128; ++h) {
        float acc = b1[h];
        for (int k = 0; k < 128; ++k) acc = fmaf(a[k], W1[(size_t)k * 128 + h], acc);
        for (int k = 0; k < 128; ++k) acc = fmaf(b[k], W1[(size_t)(128 + k) * 128 + h], acc);
        if (acc > 0.f) logit = fmaf(acc, W3[h], logit);
    }
    out[e] = 1.f / (1.f + __expf(-logit));
}

extern "C" void kernel_launch(void* const* d_in, const int* in_sizes, int n_in,
                              void* d_out, int out_size, void* d_ws, size_t ws_size,
                              hipStream_t stream) {
    const float* zi = (const float*)d_in[0];
    const float* zj = (const float*)d_in[1];
    const int*  src = (const int*)d_in[2];
    const int*  dst = (const int*)d_in[3];
    const float* W1 = (const float*)d_in[4];
    const float* b1 = (const float*)d_in[5];
    const float* W3 = (const float*)d_in[6];
    const float* b3 = (const float*)d_in[7];
    float* out = (float*)d_out;

    int nN = in_sizes[0] / DFEAT;
    int nE = in_sizes[2];
    size_t abytes = (size_t)nN * DFEAT * sizeof(unsigned short);

    if (ws_size >= 2 * abytes) {
        unsigned short* A = (unsigned short*)d_ws;
        unsigned short* B = A + (size_t)nN * DFEAT;
        // 512x2 = 1024 blocks = exactly 4/CU residency; 3-4 strips per wave
        dim3 g1(512, 2, 1);
        node_gemm<<<g1, 256, 0, stream>>>(zi, zj, W1, b1, A, B, nN);
        edge_kernel<<<2048, 256, 0, stream>>>(A, B, src, dst, W3, b3, out, nE);
    } else {
        fallback_kernel<<<(nE + 255) / 256, 256, 0, stream>>>(
            zi, zj, src, dst, W1, b1, W3, b3, out, nE);
    }
}